// Round 3
// baseline (1448.492 us; speedup 1.0000x reference)
//
#include <hip/hip_runtime.h>

// AttackLSTM R3: 6 stacked LSTM layers. B=256, T=512.
// a0:(1->64) a1:(64->64) a2:(64->64) b0:(64->1) b1:(1->1) b2:(1->1)
// R2 post-mortem: fused projection needed 128 pinned weight floats/thread but
// allocator gave 112 VGPRs -> per-step scratch spill reloads (FETCH 66MB on a
// 0.5MB-input dispatch, 1368 cy/step). R3 un-fuses:
//  - rec_k: recurrence only, 64 weights/thread (fits), quad-DPP gate gather,
//    one barrier/step, writes h [B,T,64].
//  - proj_k: h @ W_ih^T as a parallel GEMM (weights in regs, h tile broadcast
//    from LDS), writes pre in PERMUTED gate order so rec_k reads one
//    lane-contiguous float per thread per step.
//  - preb0_k: 4-gate projection for b0 (incl. biases) -> [T,B,4].
//  - b_rec_k: fused b0->b1->b2 chain, 4-deep prefetch pipeline, 4 CUs.

#define BB 256
#define TT 512

__device__ __forceinline__ float sig_(float x) {
  return __builtin_amdgcn_rcpf(1.f + __builtin_amdgcn_exp2f(-1.44269504f * x));
}
__device__ __forceinline__ float tanh_(float x) {
  return __builtin_fmaf(2.f, __builtin_amdgcn_rcpf(1.f + __builtin_amdgcn_exp2f(-2.88539008f * x)), -1.f);
}

// DPP quad_perm broadcast of quad-lane K to all 4 lanes of each quad.
template <int K>
__device__ __forceinline__ float qb_(float v) {
  return __int_as_float(__builtin_amdgcn_update_dpp(
      0, __float_as_int(v), (K | (K << 2) | (K << 4) | (K << 6)), 0xF, 0xF, true));
}

#define KEEP4(a, i) asm volatile("" : "+v"(a[(i)]), "+v"(a[(i)+1]), "+v"(a[(i)+2]), "+v"(a[(i)+3]))
#define KEEP16(a, i) do { KEEP4(a, (i)); KEEP4(a, (i)+4); KEEP4(a, (i)+8); KEEP4(a, (i)+12); } while (0)
#define KEEP64(a) do { KEEP16(a, 0); KEEP16(a, 16); KEEP16(a, 32); KEEP16(a, 48); } while (0)

// MODE 0: input = x [B,T,1] via w_ih0; MODE 1: input = pre [B,T,256] permuted.
template <int MODE, typename PreT>
__global__ __launch_bounds__(256, 1) void rec_k(
    const float* __restrict__ x,      // MODE0
    const PreT* __restrict__ pre_in,  // MODE1, permuted order (element j for thread j)
    const float* __restrict__ w_ih0,  // MODE0: [256,1]
    const float* __restrict__ w_hh,   // [256,64]
    const float* __restrict__ b_ih,
    const float* __restrict__ b_hh,
    float* __restrict__ h_out)        // [B,T,64]
{
  const int b = blockIdx.x;
  const int g = threadIdx.x;
  const int q = g & 3;    // gate: 0=i 1=f 2=g 3=o
  const int hid = g >> 2; // hidden unit 0..63
  const int row = q * 64 + hid;

  __shared__ float h_s[2][64];

  float wh[64];
  {
    const float4* p = reinterpret_cast<const float4*>(w_hh + row * 64);
#pragma unroll
    for (int i = 0; i < 16; ++i) {
      float4 v = p[i];
      wh[4 * i] = v.x; wh[4 * i + 1] = v.y; wh[4 * i + 2] = v.z; wh[4 * i + 3] = v.w;
    }
  }
  KEEP64(wh);

  const float bias = b_ih[row] + b_hh[row];
  float wi0 = 0.f;
  if constexpr (MODE == 0) wi0 = w_ih0[row];

  if (g < 64) h_s[0][g] = 0.f;
  __syncthreads();

  float c = 0.f;  // cell state for `hid` (replicated across the quad)

  float pv;
  if constexpr (MODE == 0) pv = x[(size_t)b * TT];
  else pv = (float)pre_in[((size_t)b * TT) * 256 + g];

  for (int t = 0; t < TT; ++t) {
    float nv = 0.f;
    if (t + 1 < TT) {
      if constexpr (MODE == 0) nv = x[(size_t)b * TT + t + 1];
      else nv = (float)pre_in[((size_t)b * TT + t + 1) * 256 + g];
    }

    float ar0, ar1 = 0.f, ar2 = 0.f, ar3 = 0.f;
    if constexpr (MODE == 0) ar0 = __builtin_fmaf(wi0, pv, bias);
    else ar0 = bias + pv;

    const float4* hp = reinterpret_cast<const float4*>(h_s[t & 1]);
#pragma unroll
    for (int i = 0; i < 16; ++i) {
      float4 hv = hp[i];
      ar0 = __builtin_fmaf(wh[4 * i],     hv.x, ar0);
      ar1 = __builtin_fmaf(wh[4 * i + 1], hv.y, ar1);
      ar2 = __builtin_fmaf(wh[4 * i + 2], hv.z, ar2);
      ar3 = __builtin_fmaf(wh[4 * i + 3], hv.w, ar3);
    }
    float prer = (ar0 + ar1) + (ar2 + ar3);

    float sc = (q == 2) ? -2.88539008f : -1.44269504f;
    float e = __builtin_amdgcn_exp2f(sc * prer);
    float r = __builtin_amdgcn_rcpf(1.f + e);
    float act = (q == 2) ? __builtin_fmaf(2.f, r, -1.f) : r;

    float gi = qb_<0>(act);
    float gf = qb_<1>(act);
    float gg = qb_<2>(act);
    float go = qb_<3>(act);

    c = __builtin_fmaf(gf, c, gi * gg);
    float h = go * tanh_(c);
    if (q == 0) {
      h_s[(t + 1) & 1][hid] = h;
      h_out[((size_t)b * TT + t) * 64 + hid] = h;
    }

    pv = nv;
    __syncthreads();
  }
}

// pre[row, j] = w[g,:]·h[row,:], written at j = (g&63)*4 + (g>>6) so that
// rec_k thread j (q=j&3, hid=j>>2, needs row q*64+hid) reads element j.
template <typename PreT>
__global__ __launch_bounds__(256) void proj_k(
    const float* __restrict__ h,   // [M,64], M = B*T
    const float* __restrict__ w,   // [256,64]
    PreT* __restrict__ pre)        // [M,256] permuted
{
  __shared__ float hs[64 * 64];
  const int tid = threadIdx.x;
  const int g = tid;

  float wr[64];
  {
    const float4* p = reinterpret_cast<const float4*>(w + g * 64);
#pragma unroll
    for (int i = 0; i < 16; ++i) {
      float4 v = p[i];
      wr[4 * i] = v.x; wr[4 * i + 1] = v.y; wr[4 * i + 2] = v.z; wr[4 * i + 3] = v.w;
    }
  }
  KEEP64(wr);

  const size_t base = (size_t)blockIdx.x * 64;
  {
    const float4* src = reinterpret_cast<const float4*>(h + base * 64);
    float4* dst = reinterpret_cast<float4*>(hs);
#pragma unroll
    for (int i = 0; i < 4; ++i) dst[tid + 256 * i] = src[tid + 256 * i];
  }
  __syncthreads();

  const int j = (g & 63) * 4 + (g >> 6);
  PreT* outp = pre + base * 256 + j;
  for (int r = 0; r < 64; ++r) {
    const float4* hr = reinterpret_cast<const float4*>(hs + r * 64);
    float a0 = 0.f, a1 = 0.f, a2 = 0.f, a3 = 0.f;
#pragma unroll
    for (int i = 0; i < 16; ++i) {
      float4 hv = hr[i];
      a0 = __builtin_fmaf(wr[4 * i],     hv.x, a0);
      a1 = __builtin_fmaf(wr[4 * i + 1], hv.y, a1);
      a2 = __builtin_fmaf(wr[4 * i + 2], hv.z, a2);
      a3 = __builtin_fmaf(wr[4 * i + 3], hv.w, a3);
    }
    outp[(size_t)r * 256] = (PreT)((a0 + a1) + (a2 + a3));
  }
}

// pre_b0[t,b,q] = b_ih[q]+b_hh[q] + w[q,:]·h[b,t,:]
__global__ __launch_bounds__(256) void preb0_k(
    const float* __restrict__ h,   // [M,64], rows = b*TT+t
    const float* __restrict__ w,   // [4,64]
    const float* __restrict__ bi,  // [4]
    const float* __restrict__ bh,  // [4]
    float* __restrict__ pre)       // [T,B,4]
{
  __shared__ float hs[64 * 68];  // stride 68 -> 2-way (free) bank aliasing
  const int tid = threadIdx.x;
  const int r = tid >> 2;   // row within tile 0..63
  const int q = tid & 3;    // gate

  float wr[64];
  {
    const float4* p = reinterpret_cast<const float4*>(w + q * 64);
#pragma unroll
    for (int i = 0; i < 16; ++i) {
      float4 v = p[i];
      wr[4 * i] = v.x; wr[4 * i + 1] = v.y; wr[4 * i + 2] = v.z; wr[4 * i + 3] = v.w;
    }
  }
  const float bias = bi[q] + bh[q];

  const size_t base = (size_t)blockIdx.x * 64;
  {
    const float4* src = reinterpret_cast<const float4*>(h + base * 64);
#pragma unroll
    for (int i = 0; i < 4; ++i) {
      int f = tid + 256 * i;           // float4 index 0..1023
      int rr = f >> 4, kk = f & 15;
      *reinterpret_cast<float4*>(hs + rr * 68 + kk * 4) = src[f];
    }
  }
  __syncthreads();

  const float4* hr = reinterpret_cast<const float4*>(hs + r * 68);
  float a0 = bias, a1 = 0.f, a2 = 0.f, a3 = 0.f;
#pragma unroll
  for (int i = 0; i < 16; ++i) {
    float4 hv = hr[i];
    a0 = __builtin_fmaf(wr[4 * i],     hv.x, a0);
    a1 = __builtin_fmaf(wr[4 * i + 1], hv.y, a1);
    a2 = __builtin_fmaf(wr[4 * i + 2], hv.z, a2);
    a3 = __builtin_fmaf(wr[4 * i + 3], hv.w, a3);
  }
  const size_t rowg = base + r;            // = b*TT + t
  const int b = (int)(rowg / TT), t = (int)(rowg % TT);
  pre[((size_t)t * BB + b) * 4 + q] = (a0 + a1) + (a2 + a3);
}

// Fused b0->b1->b2 recurrence, one thread per batch element, 4-deep prefetch.
__global__ __launch_bounds__(64, 1) void b_rec_k(
    const float* __restrict__ pre,      // [T,B,4]
    const float* __restrict__ w_hh_b0,
    const float* __restrict__ w_ih_b1, const float* __restrict__ w_hh_b1,
    const float* __restrict__ b_ih_b1, const float* __restrict__ b_hh_b1,
    const float* __restrict__ w_ih_b2, const float* __restrict__ w_hh_b2,
    const float* __restrict__ b_ih_b2, const float* __restrict__ b_hh_b2,
    float* __restrict__ out)            // [B,T]
{
  const int b = blockIdx.x * 64 + threadIdx.x;
  float wh0[4], wi1[4], wh1[4], bb1[4], wi2[4], wh2[4], bb2[4];
#pragma unroll
  for (int k = 0; k < 4; ++k) {
    wh0[k] = w_hh_b0[k];
    wi1[k] = w_ih_b1[k]; wh1[k] = w_hh_b1[k]; bb1[k] = b_ih_b1[k] + b_hh_b1[k];
    wi2[k] = w_ih_b2[k]; wh2[k] = w_hh_b2[k]; bb2[k] = b_ih_b2[k] + b_hh_b2[k];
  }
  float h0 = 0.f, c0 = 0.f, h1 = 0.f, c1 = 0.f, h2 = 0.f, c2 = 0.f;

  const float4* pp = reinterpret_cast<const float4*>(pre);
  float4 buf[4];
#pragma unroll
  for (int i = 0; i < 4; ++i) buf[i] = pp[i * BB + b];

  for (int t = 0; t < TT; ++t) {
    float4 p = buf[t & 3];
    if (t + 4 < TT) buf[t & 3] = pp[(t + 4) * BB + b];

    float i0 = sig_(__builtin_fmaf(wh0[0], h0, p.x));
    float f0 = sig_(__builtin_fmaf(wh0[1], h0, p.y));
    float g0 = tanh_(__builtin_fmaf(wh0[2], h0, p.z));
    float o0 = sig_(__builtin_fmaf(wh0[3], h0, p.w));
    c0 = __builtin_fmaf(f0, c0, i0 * g0);
    h0 = o0 * tanh_(c0);

    float i1 = sig_(bb1[0] + __builtin_fmaf(wi1[0], h0, wh1[0] * h1));
    float f1 = sig_(bb1[1] + __builtin_fmaf(wi1[1], h0, wh1[1] * h1));
    float g1 = tanh_(bb1[2] + __builtin_fmaf(wi1[2], h0, wh1[2] * h1));
    float o1 = sig_(bb1[3] + __builtin_fmaf(wi1[3], h0, wh1[3] * h1));
    c1 = __builtin_fmaf(f1, c1, i1 * g1);
    h1 = o1 * tanh_(c1);

    float i2 = sig_(bb2[0] + __builtin_fmaf(wi2[0], h1, wh2[0] * h2));
    float f2 = sig_(bb2[1] + __builtin_fmaf(wi2[1], h1, wh2[1] * h2));
    float g2 = tanh_(bb2[2] + __builtin_fmaf(wi2[2], h1, wh2[2] * h2));
    float o2 = sig_(bb2[3] + __builtin_fmaf(wi2[3], h1, wh2[3] * h2));
    c2 = __builtin_fmaf(f2, c2, i2 * g2);
    h2 = o2 * tanh_(c2);

    out[b * TT + t] = h2;
  }
}

template <typename PreT>
static void launch_all(void* const* d_in, void* d_out, void* d_ws, hipStream_t stream) {
  const float* x      = (const float*)d_in[0];
  const float* wih_a0 = (const float*)d_in[1];
  const float* whh_a0 = (const float*)d_in[2];
  const float* bih_a0 = (const float*)d_in[3];
  const float* bhh_a0 = (const float*)d_in[4];
  const float* wih_a1 = (const float*)d_in[5];
  const float* whh_a1 = (const float*)d_in[6];
  const float* bih_a1 = (const float*)d_in[7];
  const float* bhh_a1 = (const float*)d_in[8];
  const float* wih_a2 = (const float*)d_in[9];
  const float* whh_a2 = (const float*)d_in[10];
  const float* bih_a2 = (const float*)d_in[11];
  const float* bhh_a2 = (const float*)d_in[12];
  const float* wih_b0 = (const float*)d_in[13];
  const float* whh_b0 = (const float*)d_in[14];
  const float* bih_b0 = (const float*)d_in[15];
  const float* bhh_b0 = (const float*)d_in[16];
  const float* wih_b1 = (const float*)d_in[17];
  const float* whh_b1 = (const float*)d_in[18];
  const float* bih_b1 = (const float*)d_in[19];
  const float* bhh_b1 = (const float*)d_in[20];
  const float* wih_b2 = (const float*)d_in[21];
  const float* whh_b2 = (const float*)d_in[22];
  const float* bih_b2 = (const float*)d_in[23];
  const float* bhh_b2 = (const float*)d_in[24];

  const size_t M = (size_t)BB * TT;
  PreT* P   = (PreT*)d_ws;                                      // [M,256] permuted
  float* hA = (float*)((char*)d_ws + M * 256 * sizeof(PreT));   // [M,64]
  float* pb0 = hA + M * 64;                                     // [T,B,4]
  float* out = (float*)d_out;

  rec_k<0, PreT><<<BB, 256, 0, stream>>>(x, nullptr, wih_a0, whh_a0, bih_a0, bhh_a0, hA);
  proj_k<PreT><<<M / 64, 256, 0, stream>>>(hA, wih_a1, P);
  rec_k<1, PreT><<<BB, 256, 0, stream>>>(nullptr, P, nullptr, whh_a1, bih_a1, bhh_a1, hA);
  proj_k<PreT><<<M / 64, 256, 0, stream>>>(hA, wih_a2, P);
  rec_k<1, PreT><<<BB, 256, 0, stream>>>(nullptr, P, nullptr, whh_a2, bih_a2, bhh_a2, hA);
  preb0_k<<<M / 64, 256, 0, stream>>>(hA, wih_b0, bih_b0, bhh_b0, pb0);
  b_rec_k<<<4, 64, 0, stream>>>(pb0, whh_b0, wih_b1, whh_b1, bih_b1, bhh_b1,
                                wih_b2, whh_b2, bih_b2, bhh_b2, out);
}

extern "C" void kernel_launch(void* const* d_in, const int* in_sizes, int n_in,
                              void* d_out, int out_size, void* d_ws, size_t ws_size,
                              hipStream_t stream) {
  const size_t M = (size_t)BB * TT;
  const size_t need_f32 = M * 256 * 4 + M * 64 * 4 + (size_t)TT * BB * 4 * 4;
  if (ws_size >= need_f32) launch_all<float>(d_in, d_out, d_ws, stream);
  else launch_all<_Float16>(d_in, d_out, d_ws, stream);
}

// Round 4
// 1414.031 us; speedup vs baseline: 1.0244x; 1.0244x over previous
//
#include <hip/hip_runtime.h>

// AttackLSTM R4. B=256, T=512. a0:(1->64) a1,a2:(64->64) b0:(64->1) b1,b2:(1->1)
// R3 post-mortem: per-step __syncthreads drained an in-flight global store +
// prefetch load every step (vmcnt(0) before s_barrier) ~600+ cy/step, plus
// 64 wave-broadcast ds_read_b128/CU/step. R4:
//  - rec_k: h history in a 128-step LDS window (33 KB), bulk flush every 128
//    steps; pre prefetched 8-ahead into regs (unroll-8); raw lgkmcnt-only
//    barrier per step (global loads survive); each lane reads only its
//    16-float h chunk (4 b128), quad-DPP broadcast supplies the rest.
//  - proj_k: register-tiled GEMM (4x8 outputs/thread, transposed padded LDS).
//  - b_rec_k: fused b0->b1->b2, 8-deep prefetch, no barriers.

#define BB 256
#define TT 512
#define WIN 128

__device__ __forceinline__ float sig_(float x) {
  return __builtin_amdgcn_rcpf(1.f + __builtin_amdgcn_exp2f(-1.44269504f * x));
}
__device__ __forceinline__ float tanh_(float x) {
  return __builtin_fmaf(2.f, __builtin_amdgcn_rcpf(1.f + __builtin_amdgcn_exp2f(-2.88539008f * x)), -1.f);
}

// DPP quad_perm broadcast of quad-lane K to all 4 lanes of each quad.
template <int K>
__device__ __forceinline__ float qb_(float v) {
  return __int_as_float(__builtin_amdgcn_update_dpp(
      0, __float_as_int(v), (K | (K << 2) | (K << 4) | (K << 6)), 0xF, 0xF, true));
}

// Barrier that only waits on LDS ops: global loads/stores stay in flight.
__device__ __forceinline__ void ldsbar_() {
  asm volatile("s_waitcnt lgkmcnt(0)\n\ts_barrier" ::: "memory");
}

#define KEEP4(a, i) asm volatile("" : "+v"(a[(i)]), "+v"(a[(i)+1]), "+v"(a[(i)+2]), "+v"(a[(i)+3]))
#define KEEP16(a, i) do { KEEP4(a, (i)); KEEP4(a, (i)+4); KEEP4(a, (i)+8); KEEP4(a, (i)+12); } while (0)
#define KEEP64(a) do { KEEP16(a, 0); KEEP16(a, 16); KEEP16(a, 32); KEEP16(a, 48); } while (0)

// One phase of the dot product: broadcast quad-lane P's h chunk, FMA with
// weight rows 16P..16P+15. Fixed register indices (P is a literal).
#define PHASE(P)                                                        \
  do {                                                                  \
    _Pragma("unroll")                                                   \
    for (int m = 0; m < 16; ++m) {                                      \
      float hv = qb_<P>(hx[m]);                                         \
      acc[m & 3] = __builtin_fmaf(hv, wh[16 * (P) + m], acc[m & 3]);    \
    }                                                                   \
  } while (0)

// MODE 0: input = x [B,T,1] via w_ih0; MODE 1: input = pre [B,T,256] permuted.
template <int MODE, typename PreT>
__global__ __launch_bounds__(256, 1) void rec_k(
    const float* __restrict__ x,
    const PreT* __restrict__ pre_in,
    const float* __restrict__ w_ih0,
    const float* __restrict__ w_hh,   // [256,64]
    const float* __restrict__ b_ih,
    const float* __restrict__ b_hh,
    float* __restrict__ h_out)        // [B,T,64]
{
  const int b = blockIdx.x;
  const int g = threadIdx.x;
  const int q = g & 3;     // gate 0=i 1=f 2=g 3=o
  const int hid = g >> 2;  // hidden unit
  const int row = q * 64 + hid;

  __shared__ float hist[(WIN + 1) * 64];  // hist[u][hid]
  __shared__ float xs[TT];                // MODE0 input row

  float wh[64];
  {
    const float4* p = reinterpret_cast<const float4*>(w_hh + row * 64);
#pragma unroll
    for (int i = 0; i < 16; ++i) {
      float4 v = p[i];
      wh[4 * i] = v.x; wh[4 * i + 1] = v.y; wh[4 * i + 2] = v.z; wh[4 * i + 3] = v.w;
    }
  }
  KEEP64(wh);

  const float bias = b_ih[row] + b_hh[row];
  float wi0 = 0.f;
  if constexpr (MODE == 0) wi0 = w_ih0[row];

  if constexpr (MODE == 0) {
    xs[g] = x[(size_t)b * TT + g];
    xs[g + 256] = x[(size_t)b * TT + 256 + g];
  }
  if (g < 64) hist[g] = 0.f;

  float cur[8], nxt[8];
  if constexpr (MODE == 1) {
#pragma unroll
    for (int u = 0; u < 8; ++u) cur[u] = (float)pre_in[((size_t)b * TT + u) * 256 + g];
#pragma unroll
    for (int u = 0; u < 8; ++u) nxt[u] = (float)pre_in[((size_t)b * TT + 8 + u) * 256 + g];
  }
  __syncthreads();

  float c = 0.f;

  for (int tb = 0; tb < TT; tb += 8) {
    const int lb = tb & (WIN - 1);
#pragma unroll
    for (int u = 0; u < 8; ++u) {
      const int lu = lb + u;
      // own h chunk: hist[lu][16q .. 16q+15]
      float hx[16];
      {
        const float4* hp = reinterpret_cast<const float4*>(hist + lu * 64 + 16 * q);
        float4 h0 = hp[0], h1 = hp[1], h2 = hp[2], h3 = hp[3];
        hx[0] = h0.x; hx[1] = h0.y; hx[2] = h0.z; hx[3] = h0.w;
        hx[4] = h1.x; hx[5] = h1.y; hx[6] = h1.z; hx[7] = h1.w;
        hx[8] = h2.x; hx[9] = h2.y; hx[10] = h2.z; hx[11] = h2.w;
        hx[12] = h3.x; hx[13] = h3.y; hx[14] = h3.z; hx[15] = h3.w;
      }
      float acc[4];
      if constexpr (MODE == 0) acc[0] = __builtin_fmaf(wi0, xs[tb + u], bias);
      else acc[0] = bias + cur[u];
      acc[1] = 0.f; acc[2] = 0.f; acc[3] = 0.f;

      PHASE(0); PHASE(1); PHASE(2); PHASE(3);

      float pre = (acc[0] + acc[1]) + (acc[2] + acc[3]);
      float sc = (q == 2) ? -2.88539008f : -1.44269504f;
      float e = __builtin_amdgcn_exp2f(sc * pre);
      float r = __builtin_amdgcn_rcpf(1.f + e);
      float act = (q == 2) ? __builtin_fmaf(2.f, r, -1.f) : r;

      float gi = qb_<0>(act);
      float gf = qb_<1>(act);
      float gg = qb_<2>(act);
      float go = qb_<3>(act);

      c = __builtin_fmaf(gf, c, gi * gg);
      float h = go * tanh_(c);
      if (q == 0) hist[(lu + 1) * 64 + hid] = h;
      ldsbar_();
    }

    if constexpr (MODE == 1) {
#pragma unroll
      for (int u = 0; u < 8; ++u) cur[u] = nxt[u];
      if (tb + 16 < TT) {
#pragma unroll
        for (int u = 0; u < 8; ++u)
          nxt[u] = (float)pre_in[((size_t)b * TT + tb + 16 + u) * 256 + g];
      }
    }

    if (((tb + 8) & (WIN - 1)) == 0) {
      // flush hist[1..WIN] -> h_out rows (tb+8-WIN .. tb+7); carry hist[WIN]->hist[0]
      const int t0 = tb + 8 - WIN;
      float4* dst = reinterpret_cast<float4*>(h_out + ((size_t)b * TT + t0) * 64);
      const float4* src = reinterpret_cast<const float4*>(hist + 64);
#pragma unroll
      for (int i = 0; i < 8; ++i) dst[g + 256 * i] = src[g + 256 * i];
      if (g < 64) hist[g] = hist[WIN * 64 + g];
      ldsbar_();
    }
  }
}

// pre[rowm, pos(c)] = w[c,:]·h[rowm,:], pos(c) = (c&63)*4 + (c>>6) so rec_k
// thread j reads element j. Tiled: 64 rows x 128 cols per block.
template <typename PreT>
__global__ __launch_bounds__(256) void proj_k(
    const float* __restrict__ h,   // [M,64]
    const float* __restrict__ w,   // [256,64]
    PreT* __restrict__ pre)        // [M,256] permuted
{
  __shared__ float hs[64 * 65];    // hs[k][r]
  __shared__ float ws[64 * 132];   // ws[k][c], c in [0,128)
  const int tid = threadIdx.x;
  const int bm = blockIdx.x >> 1, half = blockIdx.x & 1;
  const size_t row0 = (size_t)bm * 64;
  const int c0 = half * 128;

#pragma unroll
  for (int i = 0; i < 16; ++i) {
    int idx = tid + 256 * i;  // 0..4095
    int r = idx >> 6, k = idx & 63;
    hs[k * 65 + r] = h[(row0 + r) * 64 + k];
  }
#pragma unroll
  for (int i = 0; i < 32; ++i) {
    int idx = tid + 256 * i;  // 0..8191
    int cc = idx >> 6, k = idx & 63;
    ws[k * 132 + cc] = w[(size_t)(c0 + cc) * 64 + k];
  }
  __syncthreads();

  const int rg = tid >> 4;  // rows 4rg..4rg+3
  const int cg = tid & 15;  // cols 8cg..8cg+7
  float acc[4][8];
#pragma unroll
  for (int r = 0; r < 4; ++r)
#pragma unroll
    for (int cc = 0; cc < 8; ++cc) acc[r][cc] = 0.f;

#pragma unroll 4
  for (int k = 0; k < 64; ++k) {
    float4 hv = *reinterpret_cast<const float4*>(&hs[k * 65 + 4 * rg]);
    float4 wa = *reinterpret_cast<const float4*>(&ws[k * 132 + 8 * cg]);
    float4 wb = *reinterpret_cast<const float4*>(&ws[k * 132 + 8 * cg + 4]);
    float hr[4] = {hv.x, hv.y, hv.z, hv.w};
    float wc[8] = {wa.x, wa.y, wa.z, wa.w, wb.x, wb.y, wb.z, wb.w};
#pragma unroll
    for (int r = 0; r < 4; ++r)
#pragma unroll
      for (int cc = 0; cc < 8; ++cc)
        acc[r][cc] = __builtin_fmaf(hr[r], wc[cc], acc[r][cc]);
  }

#pragma unroll
  for (int r = 0; r < 4; ++r) {
    size_t rowm = row0 + 4 * rg + r;
#pragma unroll
    for (int cc = 0; cc < 8; ++cc) {
      int col = c0 + 8 * cg + cc;
      int pos = (col & 63) * 4 + (col >> 6);
      pre[rowm * 256 + pos] = (PreT)acc[r][cc];
    }
  }
}

// pre_b0[t,b,q] = b_ih[q]+b_hh[q] + w[q,:]·h[b,t,:]
__global__ __launch_bounds__(256) void preb0_k(
    const float* __restrict__ h, const float* __restrict__ w,
    const float* __restrict__ bi, const float* __restrict__ bh,
    float* __restrict__ pre) {
  __shared__ float hs[64 * 68];
  const int tid = threadIdx.x;
  const int r = tid >> 2, q = tid & 3;

  float wr[64];
  {
    const float4* p = reinterpret_cast<const float4*>(w + q * 64);
#pragma unroll
    for (int i = 0; i < 16; ++i) {
      float4 v = p[i];
      wr[4 * i] = v.x; wr[4 * i + 1] = v.y; wr[4 * i + 2] = v.z; wr[4 * i + 3] = v.w;
    }
  }
  const float bias = bi[q] + bh[q];

  const size_t base = (size_t)blockIdx.x * 64;
  {
    const float4* src = reinterpret_cast<const float4*>(h + base * 64);
#pragma unroll
    for (int i = 0; i < 4; ++i) {
      int f = tid + 256 * i;
      int rr = f >> 4, kk = f & 15;
      *reinterpret_cast<float4*>(hs + rr * 68 + kk * 4) = src[f];
    }
  }
  __syncthreads();

  const float4* hr = reinterpret_cast<const float4*>(hs + r * 68);
  float a0 = bias, a1 = 0.f, a2 = 0.f, a3 = 0.f;
#pragma unroll
  for (int i = 0; i < 16; ++i) {
    float4 hv = hr[i];
    a0 = __builtin_fmaf(wr[4 * i], hv.x, a0);
    a1 = __builtin_fmaf(wr[4 * i + 1], hv.y, a1);
    a2 = __builtin_fmaf(wr[4 * i + 2], hv.z, a2);
    a3 = __builtin_fmaf(wr[4 * i + 3], hv.w, a3);
  }
  const size_t rowg = base + r;
  const int b = (int)(rowg / TT), t = (int)(rowg % TT);
  pre[((size_t)t * BB + b) * 4 + q] = (a0 + a1) + (a2 + a3);
}

// Fused b0->b1->b2, one thread per batch element, 8-deep prefetch, no barriers.
__global__ __launch_bounds__(64, 1) void b_rec_k(
    const float* __restrict__ pre,  // [T,B,4]
    const float* __restrict__ w_hh_b0,
    const float* __restrict__ w_ih_b1, const float* __restrict__ w_hh_b1,
    const float* __restrict__ b_ih_b1, const float* __restrict__ b_hh_b1,
    const float* __restrict__ w_ih_b2, const float* __restrict__ w_hh_b2,
    const float* __restrict__ b_ih_b2, const float* __restrict__ b_hh_b2,
    float* __restrict__ out) {
  const int b = blockIdx.x * 64 + threadIdx.x;
  float wh0[4], wi1[4], wh1[4], bb1[4], wi2[4], wh2[4], bb2[4];
#pragma unroll
  for (int k = 0; k < 4; ++k) {
    wh0[k] = w_hh_b0[k];
    wi1[k] = w_ih_b1[k]; wh1[k] = w_hh_b1[k]; bb1[k] = b_ih_b1[k] + b_hh_b1[k];
    wi2[k] = w_ih_b2[k]; wh2[k] = w_hh_b2[k]; bb2[k] = b_ih_b2[k] + b_hh_b2[k];
  }
  float h0 = 0.f, c0 = 0.f, h1 = 0.f, c1 = 0.f, h2 = 0.f, c2 = 0.f;

  const float4* pp = reinterpret_cast<const float4*>(pre);
  float4 buf[8];
#pragma unroll
  for (int i = 0; i < 8; ++i) buf[i] = pp[i * BB + b];

  for (int t = 0; t < TT; ++t) {
    float4 p = buf[t & 7];
    if (t + 8 < TT) buf[t & 7] = pp[(t + 8) * BB + b];

    float i0 = sig_(__builtin_fmaf(wh0[0], h0, p.x));
    float f0 = sig_(__builtin_fmaf(wh0[1], h0, p.y));
    float g0 = tanh_(__builtin_fmaf(wh0[2], h0, p.z));
    float o0 = sig_(__builtin_fmaf(wh0[3], h0, p.w));
    c0 = __builtin_fmaf(f0, c0, i0 * g0);
    h0 = o0 * tanh_(c0);

    float i1 = sig_(bb1[0] + __builtin_fmaf(wi1[0], h0, wh1[0] * h1));
    float f1 = sig_(bb1[1] + __builtin_fmaf(wi1[1], h0, wh1[1] * h1));
    float g1 = tanh_(bb1[2] + __builtin_fmaf(wi1[2], h0, wh1[2] * h1));
    float o1 = sig_(bb1[3] + __builtin_fmaf(wi1[3], h0, wh1[3] * h1));
    c1 = __builtin_fmaf(f1, c1, i1 * g1);
    h1 = o1 * tanh_(c1);

    float i2 = sig_(bb2[0] + __builtin_fmaf(wi2[0], h1, wh2[0] * h2));
    float f2 = sig_(bb2[1] + __builtin_fmaf(wi2[1], h1, wh2[1] * h2));
    float g2 = tanh_(bb2[2] + __builtin_fmaf(wi2[2], h1, wh2[2] * h2));
    float o2 = sig_(bb2[3] + __builtin_fmaf(wi2[3], h1, wh2[3] * h2));
    c2 = __builtin_fmaf(f2, c2, i2 * g2);
    h2 = o2 * tanh_(c2);

    out[b * TT + t] = h2;
  }
}

template <typename PreT>
static void launch_all(void* const* d_in, void* d_out, void* d_ws, hipStream_t stream) {
  const float* x      = (const float*)d_in[0];
  const float* wih_a0 = (const float*)d_in[1];
  const float* whh_a0 = (const float*)d_in[2];
  const float* bih_a0 = (const float*)d_in[3];
  const float* bhh_a0 = (const float*)d_in[4];
  const float* wih_a1 = (const float*)d_in[5];
  const float* whh_a1 = (const float*)d_in[6];
  const float* bih_a1 = (const float*)d_in[7];
  const float* bhh_a1 = (const float*)d_in[8];
  const float* wih_a2 = (const float*)d_in[9];
  const float* whh_a2 = (const float*)d_in[10];
  const float* bih_a2 = (const float*)d_in[11];
  const float* bhh_a2 = (const float*)d_in[12];
  const float* wih_b0 = (const float*)d_in[13];
  const float* whh_b0 = (const float*)d_in[14];
  const float* bih_b0 = (const float*)d_in[15];
  const float* bhh_b0 = (const float*)d_in[16];
  const float* wih_b1 = (const float*)d_in[17];
  const float* whh_b1 = (const float*)d_in[18];
  const float* bih_b1 = (const float*)d_in[19];
  const float* bhh_b1 = (const float*)d_in[20];
  const float* wih_b2 = (const float*)d_in[21];
  const float* whh_b2 = (const float*)d_in[22];
  const float* bih_b2 = (const float*)d_in[23];
  const float* bhh_b2 = (const float*)d_in[24];

  const size_t M = (size_t)BB * TT;
  PreT* P   = (PreT*)d_ws;                                     // [M,256] permuted
  float* hA = (float*)((char*)d_ws + M * 256 * sizeof(PreT));  // [M,64]
  float* pb0 = hA + M * 64;                                    // [T,B,4]
  float* out = (float*)d_out;

  rec_k<0, PreT><<<BB, 256, 0, stream>>>(x, nullptr, wih_a0, whh_a0, bih_a0, bhh_a0, hA);
  proj_k<PreT><<<(int)(M / 64) * 2, 256, 0, stream>>>(hA, wih_a1, P);
  rec_k<1, PreT><<<BB, 256, 0, stream>>>(nullptr, P, nullptr, whh_a1, bih_a1, bhh_a1, hA);
  proj_k<PreT><<<(int)(M / 64) * 2, 256, 0, stream>>>(hA, wih_a2, P);
  rec_k<1, PreT><<<BB, 256, 0, stream>>>(nullptr, P, nullptr, whh_a2, bih_a2, bhh_a2, hA);
  preb0_k<<<(int)(M / 64), 256, 0, stream>>>(hA, wih_b0, bih_b0, bhh_b0, pb0);
  b_rec_k<<<4, 64, 0, stream>>>(pb0, whh_b0, wih_b1, whh_b1, bih_b1, bhh_b1,
                                wih_b2, whh_b2, bih_b2, bhh_b2, out);
}

extern "C" void kernel_launch(void* const* d_in, const int* in_sizes, int n_in,
                              void* d_out, int out_size, void* d_ws, size_t ws_size,
                              hipStream_t stream) {
  const size_t M = (size_t)BB * TT;
  const size_t need_f32 = M * 256 * 4 + M * 64 * 4 + (size_t)TT * BB * 4 * 4;
  if (ws_size >= need_f32) launch_all<float>(d_in, d_out, d_ws, stream);
  else launch_all<_Float16>(d_in, d_out, d_ws, stream);
}

// Round 5
// 1072.095 us; speedup vs baseline: 1.3511x; 1.3189x over previous
//
#include <hip/hip_runtime.h>

// AttackLSTM R5. B=256, T=512. a0:(1->64) a1,a2:(64->64) b0:(64->1) b1,b2:(1->1)
// R4 post-mortem: b_rec_k's buf[t&7] dynamic index demoted the prefetch array
// to scratch (VGPR_Count=28 < 32 needed) -> ~1400 cy/step scratch round-trip,
// VALUBusy 0.13%. R5:
//  - b_rec_k: chunk-8 fully-unrolled register pipeline (static indices),
//    float4-batched output stores.
//  - rec_k: 16 accumulators (FMA chain 16->4 deep) + balanced reduction.
//  - proj_k: identity-layout coalesced stores; permutation moved to rec_k's
//    read side (constant per-lane offset, L1-resident segment).

#define BB 256
#define TT 512
#define WIN 128

__device__ __forceinline__ float sig_(float x) {
  return __builtin_amdgcn_rcpf(1.f + __builtin_amdgcn_exp2f(-1.44269504f * x));
}
__device__ __forceinline__ float tanh_(float x) {
  return __builtin_fmaf(2.f, __builtin_amdgcn_rcpf(1.f + __builtin_amdgcn_exp2f(-2.88539008f * x)), -1.f);
}

// DPP quad_perm broadcast of quad-lane K to all 4 lanes of each quad.
template <int K>
__device__ __forceinline__ float qb_(float v) {
  return __int_as_float(__builtin_amdgcn_update_dpp(
      0, __float_as_int(v), (K | (K << 2) | (K << 4) | (K << 6)), 0xF, 0xF, true));
}

// Barrier that only waits on LDS ops: global loads/stores stay in flight.
__device__ __forceinline__ void ldsbar_() {
  asm volatile("s_waitcnt lgkmcnt(0)\n\ts_barrier" ::: "memory");
}

#define KEEP4(a, i) asm volatile("" : "+v"(a[(i)]), "+v"(a[(i)+1]), "+v"(a[(i)+2]), "+v"(a[(i)+3]))
#define KEEP16(a, i) do { KEEP4(a, (i)); KEEP4(a, (i)+4); KEEP4(a, (i)+8); KEEP4(a, (i)+12); } while (0)
#define KEEP64(a) do { KEEP16(a, 0); KEEP16(a, 16); KEEP16(a, 32); KEEP16(a, 48); } while (0)

// One phase: broadcast quad-lane P's h chunk, FMA into 16 accumulators.
#define PHASE(P)                                                   \
  do {                                                             \
    _Pragma("unroll")                                              \
    for (int m = 0; m < 16; ++m) {                                 \
      float hv = qb_<P>(hx[m]);                                    \
      acc[m] = __builtin_fmaf(hv, wh[16 * (P) + m], acc[m]);       \
    }                                                              \
  } while (0)

// MODE 0: input = x [B,T,1] via w_ih0; MODE 1: input = pre [B,T,256] identity
// layout; thread g reads element (g&3)*64 + (g>>2) (its gate row's value).
template <int MODE, typename PreT>
__global__ __launch_bounds__(256, 1) void rec_k(
    const float* __restrict__ x,
    const PreT* __restrict__ pre_in,
    const float* __restrict__ w_ih0,
    const float* __restrict__ w_hh,   // [256,64]
    const float* __restrict__ b_ih,
    const float* __restrict__ b_hh,
    float* __restrict__ h_out)        // [B,T,64]
{
  const int b = blockIdx.x;
  const int g = threadIdx.x;
  const int q = g & 3;     // gate 0=i 1=f 2=g 3=o
  const int hid = g >> 2;  // hidden unit
  const int row = q * 64 + hid;
  const int ofs = q * 64 + hid;  // read offset into identity-layout pre row

  __shared__ float hist[(WIN + 1) * 64];  // hist[u][hid]
  __shared__ float xs[TT];                // MODE0 input row

  float wh[64];
  {
    const float4* p = reinterpret_cast<const float4*>(w_hh + row * 64);
#pragma unroll
    for (int i = 0; i < 16; ++i) {
      float4 v = p[i];
      wh[4 * i] = v.x; wh[4 * i + 1] = v.y; wh[4 * i + 2] = v.z; wh[4 * i + 3] = v.w;
    }
  }
  KEEP64(wh);

  const float bias = b_ih[row] + b_hh[row];
  float wi0 = 0.f;
  if constexpr (MODE == 0) wi0 = w_ih0[row];

  if constexpr (MODE == 0) {
    xs[g] = x[(size_t)b * TT + g];
    xs[g + 256] = x[(size_t)b * TT + 256 + g];
  }
  if (g < 64) hist[g] = 0.f;

  float cur[8], nxt[8];
  if constexpr (MODE == 1) {
#pragma unroll
    for (int u = 0; u < 8; ++u) cur[u] = (float)pre_in[((size_t)b * TT + u) * 256 + ofs];
#pragma unroll
    for (int u = 0; u < 8; ++u) nxt[u] = (float)pre_in[((size_t)b * TT + 8 + u) * 256 + ofs];
  }
  __syncthreads();

  float c = 0.f;

  for (int tb = 0; tb < TT; tb += 8) {
    const int lb = tb & (WIN - 1);
#pragma unroll
    for (int u = 0; u < 8; ++u) {
      const int lu = lb + u;
      // own h chunk: hist[lu][16q .. 16q+15]
      float hx[16];
      {
        const float4* hp = reinterpret_cast<const float4*>(hist + lu * 64 + 16 * q);
        float4 h0 = hp[0], h1 = hp[1], h2 = hp[2], h3 = hp[3];
        hx[0] = h0.x; hx[1] = h0.y; hx[2] = h0.z; hx[3] = h0.w;
        hx[4] = h1.x; hx[5] = h1.y; hx[6] = h1.z; hx[7] = h1.w;
        hx[8] = h2.x; hx[9] = h2.y; hx[10] = h2.z; hx[11] = h2.w;
        hx[12] = h3.x; hx[13] = h3.y; hx[14] = h3.z; hx[15] = h3.w;
      }
      float acc[16];
      if constexpr (MODE == 0) acc[0] = __builtin_fmaf(wi0, xs[tb + u], bias);
      else acc[0] = bias + cur[u];
#pragma unroll
      for (int m = 1; m < 16; ++m) acc[m] = 0.f;

      PHASE(0); PHASE(1); PHASE(2); PHASE(3);

      // balanced reduction of 16 accumulators
      float s0 = acc[0] + acc[1], s1 = acc[2] + acc[3];
      float s2 = acc[4] + acc[5], s3 = acc[6] + acc[7];
      float s4 = acc[8] + acc[9], s5 = acc[10] + acc[11];
      float s6 = acc[12] + acc[13], s7 = acc[14] + acc[15];
      float r0 = s0 + s1, r1 = s2 + s3, r2 = s4 + s5, r3 = s6 + s7;
      float pre = (r0 + r1) + (r2 + r3);

      float sc = (q == 2) ? -2.88539008f : -1.44269504f;
      float e = __builtin_amdgcn_exp2f(sc * pre);
      float r = __builtin_amdgcn_rcpf(1.f + e);
      float act = (q == 2) ? __builtin_fmaf(2.f, r, -1.f) : r;

      float gi = qb_<0>(act);
      float gf = qb_<1>(act);
      float gg = qb_<2>(act);
      float go = qb_<3>(act);

      c = __builtin_fmaf(gf, c, gi * gg);
      float h = go * tanh_(c);
      if (q == 0) hist[(lu + 1) * 64 + hid] = h;
      ldsbar_();
    }

    if constexpr (MODE == 1) {
#pragma unroll
      for (int u = 0; u < 8; ++u) cur[u] = nxt[u];
      if (tb + 16 < TT) {
#pragma unroll
        for (int u = 0; u < 8; ++u)
          nxt[u] = (float)pre_in[((size_t)b * TT + tb + 16 + u) * 256 + ofs];
      }
    }

    if (((tb + 8) & (WIN - 1)) == 0) {
      // flush hist[1..WIN] -> h_out rows (tb+8-WIN .. tb+7); carry last->hist[0]
      const int t0 = tb + 8 - WIN;
      float4* dst = reinterpret_cast<float4*>(h_out + ((size_t)b * TT + t0) * 64);
      const float4* src = reinterpret_cast<const float4*>(hist + 64);
#pragma unroll
      for (int i = 0; i < 8; ++i) dst[g + 256 * i] = src[g + 256 * i];
      if (g < 64) hist[g] = hist[WIN * 64 + g];
      ldsbar_();
    }
  }
}

// pre[rowm, c] = w[c,:]·h[rowm,:] (identity layout, coalesced stores).
// Tiled: 64 rows x 128 cols per block; thread computes 4x8.
template <typename PreT>
__global__ __launch_bounds__(256) void proj_k(
    const float* __restrict__ h,   // [M,64]
    const float* __restrict__ w,   // [256,64]
    PreT* __restrict__ pre)        // [M,256]
{
  __shared__ float hs[64 * 65];    // hs[k][r]
  __shared__ float ws[64 * 132];   // ws[k][c], c in [0,128)
  const int tid = threadIdx.x;
  const int bm = blockIdx.x >> 1, half = blockIdx.x & 1;
  const size_t row0 = (size_t)bm * 64;
  const int c0 = half * 128;

#pragma unroll
  for (int i = 0; i < 16; ++i) {
    int idx = tid + 256 * i;  // 0..4095
    int r = idx >> 6, k = idx & 63;
    hs[k * 65 + r] = h[(row0 + r) * 64 + k];
  }
#pragma unroll
  for (int i = 0; i < 32; ++i) {
    int idx = tid + 256 * i;  // 0..8191
    int cc = idx >> 6, k = idx & 63;
    ws[k * 132 + cc] = w[(size_t)(c0 + cc) * 64 + k];
  }
  __syncthreads();

  const int rg = tid >> 4;  // rows 4rg..4rg+3
  const int cg = tid & 15;  // cols 8cg..8cg+7
  float acc[4][8];
#pragma unroll
  for (int r = 0; r < 4; ++r)
#pragma unroll
    for (int cc = 0; cc < 8; ++cc) acc[r][cc] = 0.f;

#pragma unroll 4
  for (int k = 0; k < 64; ++k) {
    float4 hv = *reinterpret_cast<const float4*>(&hs[k * 65 + 4 * rg]);
    float4 wa = *reinterpret_cast<const float4*>(&ws[k * 132 + 8 * cg]);
    float4 wb = *reinterpret_cast<const float4*>(&ws[k * 132 + 8 * cg + 4]);
    float hr[4] = {hv.x, hv.y, hv.z, hv.w};
    float wc[8] = {wa.x, wa.y, wa.z, wa.w, wb.x, wb.y, wb.z, wb.w};
#pragma unroll
    for (int r = 0; r < 4; ++r)
#pragma unroll
      for (int cc = 0; cc < 8; ++cc)
        acc[r][cc] = __builtin_fmaf(hr[r], wc[cc], acc[r][cc]);
  }

#pragma unroll
  for (int r = 0; r < 4; ++r) {
    size_t rowm = row0 + 4 * rg + r;
    PreT* dst = pre + rowm * 256 + c0 + 8 * cg;  // 32B-aligned contiguous run
#pragma unroll
    for (int cc = 0; cc < 8; ++cc) dst[cc] = (PreT)acc[r][cc];
  }
}

// pre_b0[t,b,q] = b_ih[q]+b_hh[q] + w[q,:]·h[b,t,:]
__global__ __launch_bounds__(256) void preb0_k(
    const float* __restrict__ h, const float* __restrict__ w,
    const float* __restrict__ bi, const float* __restrict__ bh,
    float* __restrict__ pre) {
  __shared__ float hs[64 * 68];
  const int tid = threadIdx.x;
  const int r = tid >> 2, q = tid & 3;

  float wr[64];
  {
    const float4* p = reinterpret_cast<const float4*>(w + q * 64);
#pragma unroll
    for (int i = 0; i < 16; ++i) {
      float4 v = p[i];
      wr[4 * i] = v.x; wr[4 * i + 1] = v.y; wr[4 * i + 2] = v.z; wr[4 * i + 3] = v.w;
    }
  }
  const float bias = bi[q] + bh[q];

  const size_t base = (size_t)blockIdx.x * 64;
  {
    const float4* src = reinterpret_cast<const float4*>(h + base * 64);
#pragma unroll
    for (int i = 0; i < 4; ++i) {
      int f = tid + 256 * i;
      int rr = f >> 4, kk = f & 15;
      *reinterpret_cast<float4*>(hs + rr * 68 + kk * 4) = src[f];
    }
  }
  __syncthreads();

  const float4* hr = reinterpret_cast<const float4*>(hs + r * 68);
  float a0 = bias, a1 = 0.f, a2 = 0.f, a3 = 0.f;
#pragma unroll
  for (int i = 0; i < 16; ++i) {
    float4 hv = hr[i];
    a0 = __builtin_fmaf(wr[4 * i], hv.x, a0);
    a1 = __builtin_fmaf(wr[4 * i + 1], hv.y, a1);
    a2 = __builtin_fmaf(wr[4 * i + 2], hv.z, a2);
    a3 = __builtin_fmaf(wr[4 * i + 3], hv.w, a3);
  }
  const size_t rowg = base + r;
  const int b = (int)(rowg / TT), t = (int)(rowg % TT);
  pre[((size_t)t * BB + b) * 4 + q] = (a0 + a1) + (a2 + a3);
}

// Fused b0->b1->b2, one thread per batch element, chunk-8 register pipeline
// with STATIC indices (no scratch), float4-batched output stores.
__global__ __launch_bounds__(64, 1) void b_rec_k(
    const float* __restrict__ pre,  // [T,B,4]
    const float* __restrict__ w_hh_b0,
    const float* __restrict__ w_ih_b1, const float* __restrict__ w_hh_b1,
    const float* __restrict__ b_ih_b1, const float* __restrict__ b_hh_b1,
    const float* __restrict__ w_ih_b2, const float* __restrict__ w_hh_b2,
    const float* __restrict__ b_ih_b2, const float* __restrict__ b_hh_b2,
    float* __restrict__ out) {
  const int b = blockIdx.x * 64 + threadIdx.x;
  float wh0[4], wi1[4], wh1[4], bb1[4], wi2[4], wh2[4], bb2[4];
#pragma unroll
  for (int k = 0; k < 4; ++k) {
    wh0[k] = w_hh_b0[k];
    wi1[k] = w_ih_b1[k]; wh1[k] = w_hh_b1[k]; bb1[k] = b_ih_b1[k] + b_hh_b1[k];
    wi2[k] = w_ih_b2[k]; wh2[k] = w_hh_b2[k]; bb2[k] = b_ih_b2[k] + b_hh_b2[k];
  }
  float h0 = 0.f, c0 = 0.f, h1 = 0.f, c1 = 0.f, h2 = 0.f, c2 = 0.f;

  const float4* pp = reinterpret_cast<const float4*>(pre);
  float4 cur[8], nxt[8];
#pragma unroll
  for (int u = 0; u < 8; ++u) cur[u] = pp[u * BB + b];
#pragma unroll
  for (int u = 0; u < 8; ++u) nxt[u] = pp[(8 + u) * BB + b];

  for (int tb = 0; tb < TT; tb += 8) {
    float ob[8];
#pragma unroll
    for (int u = 0; u < 8; ++u) {
      float4 p = cur[u];
      float i0 = sig_(__builtin_fmaf(wh0[0], h0, p.x));
      float f0 = sig_(__builtin_fmaf(wh0[1], h0, p.y));
      float g0 = tanh_(__builtin_fmaf(wh0[2], h0, p.z));
      float o0 = sig_(__builtin_fmaf(wh0[3], h0, p.w));
      c0 = __builtin_fmaf(f0, c0, i0 * g0);
      h0 = o0 * tanh_(c0);

      float i1 = sig_(bb1[0] + __builtin_fmaf(wi1[0], h0, wh1[0] * h1));
      float f1 = sig_(bb1[1] + __builtin_fmaf(wi1[1], h0, wh1[1] * h1));
      float g1 = tanh_(bb1[2] + __builtin_fmaf(wi1[2], h0, wh1[2] * h1));
      float o1 = sig_(bb1[3] + __builtin_fmaf(wi1[3], h0, wh1[3] * h1));
      c1 = __builtin_fmaf(f1, c1, i1 * g1);
      h1 = o1 * tanh_(c1);

      float i2 = sig_(bb2[0] + __builtin_fmaf(wi2[0], h1, wh2[0] * h2));
      float f2 = sig_(bb2[1] + __builtin_fmaf(wi2[1], h1, wh2[1] * h2));
      float g2 = tanh_(bb2[2] + __builtin_fmaf(wi2[2], h1, wh2[2] * h2));
      float o2 = sig_(bb2[3] + __builtin_fmaf(wi2[3], h1, wh2[3] * h2));
      c2 = __builtin_fmaf(f2, c2, i2 * g2);
      h2 = o2 * tanh_(c2);
      ob[u] = h2;
    }
    float4 s0 = {ob[0], ob[1], ob[2], ob[3]};
    float4 s1 = {ob[4], ob[5], ob[6], ob[7]};
    float4* op = reinterpret_cast<float4*>(out + (size_t)b * TT + tb);
    op[0] = s0;
    op[1] = s1;
#pragma unroll
    for (int u = 0; u < 8; ++u) cur[u] = nxt[u];
    if (tb + 16 < TT) {
#pragma unroll
      for (int u = 0; u < 8; ++u) nxt[u] = pp[(tb + 16 + u) * BB + b];
    }
  }
}

template <typename PreT>
static void launch_all(void* const* d_in, void* d_out, void* d_ws, hipStream_t stream) {
  const float* x      = (const float*)d_in[0];
  const float* wih_a0 = (const float*)d_in[1];
  const float* whh_a0 = (const float*)d_in[2];
  const float* bih_a0 = (const float*)d_in[3];
  const float* bhh_a0 = (const float*)d_in[4];
  const float* wih_a1 = (const float*)d_in[5];
  const float* whh_a1 = (const float*)d_in[6];
  const float* bih_a1 = (const float*)d_in[7];
  const float* bhh_a1 = (const float*)d_in[8];
  const float* wih_a2 = (const float*)d_in[9];
  const float* whh_a2 = (const float*)d_in[10];
  const float* bih_a2 = (const float*)d_in[11];
  const float* bhh_a2 = (const float*)d_in[12];
  const float* wih_b0 = (const float*)d_in[13];
  const float* whh_b0 = (const float*)d_in[14];
  const float* bih_b0 = (const float*)d_in[15];
  const float* bhh_b0 = (const float*)d_in[16];
  const float* wih_b1 = (const float*)d_in[17];
  const float* whh_b1 = (const float*)d_in[18];
  const float* bih_b1 = (const float*)d_in[19];
  const float* bhh_b1 = (const float*)d_in[20];
  const float* wih_b2 = (const float*)d_in[21];
  const float* whh_b2 = (const float*)d_in[22];
  const float* bih_b2 = (const float*)d_in[23];
  const float* bhh_b2 = (const float*)d_in[24];

  const size_t M = (size_t)BB * TT;
  PreT* P   = (PreT*)d_ws;                                     // [M,256]
  float* hA = (float*)((char*)d_ws + M * 256 * sizeof(PreT));  // [M,64]
  float* pb0 = hA + M * 64;                                    // [T,B,4]
  float* out = (float*)d_out;

  rec_k<0, PreT><<<BB, 256, 0, stream>>>(x, nullptr, wih_a0, whh_a0, bih_a0, bhh_a0, hA);
  proj_k<PreT><<<(int)(M / 64) * 2, 256, 0, stream>>>(hA, wih_a1, P);
  rec_k<1, PreT><<<BB, 256, 0, stream>>>(nullptr, P, nullptr, whh_a1, bih_a1, bhh_a1, hA);
  proj_k<PreT><<<(int)(M / 64) * 2, 256, 0, stream>>>(hA, wih_a2, P);
  rec_k<1, PreT><<<BB, 256, 0, stream>>>(nullptr, P, nullptr, whh_a2, bih_a2, bhh_a2, hA);
  preb0_k<<<(int)(M / 64), 256, 0, stream>>>(hA, wih_b0, bih_b0, bhh_b0, pb0);
  b_rec_k<<<4, 64, 0, stream>>>(pb0, whh_b0, wih_b1, whh_b1, bih_b1, bhh_b1,
                                wih_b2, whh_b2, bih_b2, bhh_b2, out);
}

extern "C" void kernel_launch(void* const* d_in, const int* in_sizes, int n_in,
                              void* d_out, int out_size, void* d_ws, size_t ws_size,
                              hipStream_t stream) {
  const size_t M = (size_t)BB * TT;
  const size_t need_f32 = M * 256 * 4 + M * 64 * 4 + (size_t)TT * BB * 4 * 4;
  if (ws_size >= need_f32) launch_all<float>(d_in, d_out, d_ws, stream);
  else launch_all<_Float16>(d_in, d_out, d_ws, stream);
}

// Round 6
// 915.353 us; speedup vs baseline: 1.5824x; 1.1712x over previous
//
#include <hip/hip_runtime.h>

// AttackLSTM R6. B=256, T=512. a0:(1->64) a1,a2:(64->64) b0:(64->1) b1,b2:(1->1)
// R5 post-mortem: rec_k 262us x3 dominates; 1230 cy/step with 56% VALUBusy.
// Dot = 64 v_mov_dpp + 64 v_fma = 128 VALU/step. R6 fuses the quad-broadcast
// into the FMA with v_fmac_f32_dpp (DPP on VOP2 src0) -> 64 insts/step, and
// trims accumulators 16->8. Everything else (proj/preb0/b_rec) unchanged.

#define BB 256
#define TT 512
#define WIN 128

__device__ __forceinline__ float sig_(float x) {
  return __builtin_amdgcn_rcpf(1.f + __builtin_amdgcn_exp2f(-1.44269504f * x));
}
__device__ __forceinline__ float tanh_(float x) {
  return __builtin_fmaf(2.f, __builtin_amdgcn_rcpf(1.f + __builtin_amdgcn_exp2f(-2.88539008f * x)), -1.f);
}

// DPP quad_perm broadcast of quad-lane K to all 4 lanes of each quad.
template <int K>
__device__ __forceinline__ float qb_(float v) {
  return __int_as_float(__builtin_amdgcn_update_dpp(
      0, __float_as_int(v), (K | (K << 2) | (K << 4) | (K << 6)), 0xF, 0xF, true));
}

// Barrier that only waits on LDS ops: global loads/stores stay in flight.
__device__ __forceinline__ void ldsbar_() {
  asm volatile("s_waitcnt lgkmcnt(0)\n\ts_barrier" ::: "memory");
}

#define KEEP4(a, i) asm volatile("" : "+v"(a[(i)]), "+v"(a[(i)+1]), "+v"(a[(i)+2]), "+v"(a[(i)+3]))
#define KEEP16(a, i) do { KEEP4(a, (i)); KEEP4(a, (i)+4); KEEP4(a, (i)+8); KEEP4(a, (i)+12); } while (0)
#define KEEP64(a) do { KEEP16(a, 0); KEEP16(a, 16); KEEP16(a, 32); KEEP16(a, 48); } while (0)

// Fused broadcast+FMA: acc += quad_broadcast<P>(h) * w  (one VOP2-DPP inst).
// h is only ever written by ds_read (no VALU->DPP hazard).
#define QPSTR(P) "quad_perm:[" #P "," #P "," #P "," #P "]"
#define FMACD(a, h, w, P)                                             \
  asm("v_fmac_f32_dpp %0, %1, %2 " QPSTR(P) " row_mask:0xf bank_mask:0xf" \
      : "+v"(a) : "v"(h), "v"(w))
#define FM(P, M) FMACD(acc[(M) & 7], hx[M], wh[16 * (P) + (M)], P)
#define PHASE(P)                                                     \
  do {                                                               \
    FM(P, 0); FM(P, 1); FM(P, 2); FM(P, 3);                          \
    FM(P, 4); FM(P, 5); FM(P, 6); FM(P, 7);                          \
    FM(P, 8); FM(P, 9); FM(P, 10); FM(P, 11);                        \
    FM(P, 12); FM(P, 13); FM(P, 14); FM(P, 15);                      \
  } while (0)

// MODE 0: input = x [B,T,1] via w_ih0; MODE 1: input = pre [B,T,256] identity
// layout; thread g reads element (g&3)*64 + (g>>2) of its row.
template <int MODE, typename PreT>
__global__ __launch_bounds__(256, 1) void rec_k(
    const float* __restrict__ x,
    const PreT* __restrict__ pre_in,
    const float* __restrict__ w_ih0,
    const float* __restrict__ w_hh,   // [256,64]
    const float* __restrict__ b_ih,
    const float* __restrict__ b_hh,
    float* __restrict__ h_out)        // [B,T,64]
{
  const int b = blockIdx.x;
  const int g = threadIdx.x;
  const int q = g & 3;     // gate 0=i 1=f 2=g 3=o
  const int hid = g >> 2;  // hidden unit
  const int row = q * 64 + hid;
  const int ofs = q * 64 + hid;

  __shared__ float hist[(WIN + 1) * 64];  // hist[u][hid]
  __shared__ float xs[TT];                // MODE0 input row

  float wh[64];
  {
    const float4* p = reinterpret_cast<const float4*>(w_hh + row * 64);
#pragma unroll
    for (int i = 0; i < 16; ++i) {
      float4 v = p[i];
      wh[4 * i] = v.x; wh[4 * i + 1] = v.y; wh[4 * i + 2] = v.z; wh[4 * i + 3] = v.w;
    }
  }
  KEEP64(wh);

  const float bias = b_ih[row] + b_hh[row];
  float wi0 = 0.f;
  if constexpr (MODE == 0) wi0 = w_ih0[row];

  if constexpr (MODE == 0) {
    xs[g] = x[(size_t)b * TT + g];
    xs[g + 256] = x[(size_t)b * TT + 256 + g];
  }
  if (g < 64) hist[g] = 0.f;

  float cur[8], nxt[8];
  if constexpr (MODE == 1) {
#pragma unroll
    for (int u = 0; u < 8; ++u) cur[u] = (float)pre_in[((size_t)b * TT + u) * 256 + ofs];
#pragma unroll
    for (int u = 0; u < 8; ++u) nxt[u] = (float)pre_in[((size_t)b * TT + 8 + u) * 256 + ofs];
  }
  __syncthreads();

  float c = 0.f;

  for (int tb = 0; tb < TT; tb += 8) {
    const int lb = tb & (WIN - 1);
#pragma unroll
    for (int u = 0; u < 8; ++u) {
      const int lu = lb + u;
      // own h chunk: hist[lu][16q .. 16q+15]
      float hx[16];
      {
        const float4* hp = reinterpret_cast<const float4*>(hist + lu * 64 + 16 * q);
        float4 h0 = hp[0], h1 = hp[1], h2 = hp[2], h3 = hp[3];
        hx[0] = h0.x; hx[1] = h0.y; hx[2] = h0.z; hx[3] = h0.w;
        hx[4] = h1.x; hx[5] = h1.y; hx[6] = h1.z; hx[7] = h1.w;
        hx[8] = h2.x; hx[9] = h2.y; hx[10] = h2.z; hx[11] = h2.w;
        hx[12] = h3.x; hx[13] = h3.y; hx[14] = h3.z; hx[15] = h3.w;
      }
      float acc[8];
      if constexpr (MODE == 0) acc[0] = __builtin_fmaf(wi0, xs[tb + u], bias);
      else acc[0] = bias + cur[u];
#pragma unroll
      for (int m = 1; m < 8; ++m) acc[m] = 0.f;

      PHASE(0); PHASE(1); PHASE(2); PHASE(3);

      float s0 = acc[0] + acc[1], s1 = acc[2] + acc[3];
      float s2 = acc[4] + acc[5], s3 = acc[6] + acc[7];
      float pre = (s0 + s1) + (s2 + s3);

      float sc = (q == 2) ? -2.88539008f : -1.44269504f;
      float e = __builtin_amdgcn_exp2f(sc * pre);
      float r = __builtin_amdgcn_rcpf(1.f + e);
      float act = (q == 2) ? __builtin_fmaf(2.f, r, -1.f) : r;

      float gi = qb_<0>(act);
      float gf = qb_<1>(act);
      float gg = qb_<2>(act);
      float go = qb_<3>(act);

      c = __builtin_fmaf(gf, c, gi * gg);
      float h = go * tanh_(c);
      if (q == 0) hist[(lu + 1) * 64 + hid] = h;
      ldsbar_();
    }

    if constexpr (MODE == 1) {
#pragma unroll
      for (int u = 0; u < 8; ++u) cur[u] = nxt[u];
      if (tb + 16 < TT) {
#pragma unroll
        for (int u = 0; u < 8; ++u)
          nxt[u] = (float)pre_in[((size_t)b * TT + tb + 16 + u) * 256 + ofs];
      }
    }

    if (((tb + 8) & (WIN - 1)) == 0) {
      const int t0 = tb + 8 - WIN;
      float4* dst = reinterpret_cast<float4*>(h_out + ((size_t)b * TT + t0) * 64);
      const float4* src = reinterpret_cast<const float4*>(hist + 64);
#pragma unroll
      for (int i = 0; i < 8; ++i) dst[g + 256 * i] = src[g + 256 * i];
      if (g < 64) hist[g] = hist[WIN * 64 + g];
      ldsbar_();
    }
  }
}

// pre[rowm, c] = w[c,:]·h[rowm,:] (identity layout, coalesced stores).
template <typename PreT>
__global__ __launch_bounds__(256) void proj_k(
    const float* __restrict__ h,   // [M,64]
    const float* __restrict__ w,   // [256,64]
    PreT* __restrict__ pre)        // [M,256]
{
  __shared__ float hs[64 * 65];    // hs[k][r]
  __shared__ float ws[64 * 132];   // ws[k][c]
  const int tid = threadIdx.x;
  const int bm = blockIdx.x >> 1, half = blockIdx.x & 1;
  const size_t row0 = (size_t)bm * 64;
  const int c0 = half * 128;

#pragma unroll
  for (int i = 0; i < 16; ++i) {
    int idx = tid + 256 * i;
    int r = idx >> 6, k = idx & 63;
    hs[k * 65 + r] = h[(row0 + r) * 64 + k];
  }
#pragma unroll
  for (int i = 0; i < 32; ++i) {
    int idx = tid + 256 * i;
    int cc = idx >> 6, k = idx & 63;
    ws[k * 132 + cc] = w[(size_t)(c0 + cc) * 64 + k];
  }
  __syncthreads();

  const int rg = tid >> 4;
  const int cg = tid & 15;
  float acc[4][8];
#pragma unroll
  for (int r = 0; r < 4; ++r)
#pragma unroll
    for (int cc = 0; cc < 8; ++cc) acc[r][cc] = 0.f;

#pragma unroll 4
  for (int k = 0; k < 64; ++k) {
    float4 hv = *reinterpret_cast<const float4*>(&hs[k * 65 + 4 * rg]);
    float4 wa = *reinterpret_cast<const float4*>(&ws[k * 132 + 8 * cg]);
    float4 wb = *reinterpret_cast<const float4*>(&ws[k * 132 + 8 * cg + 4]);
    float hr[4] = {hv.x, hv.y, hv.z, hv.w};
    float wc[8] = {wa.x, wa.y, wa.z, wa.w, wb.x, wb.y, wb.z, wb.w};
#pragma unroll
    for (int r = 0; r < 4; ++r)
#pragma unroll
      for (int cc = 0; cc < 8; ++cc)
        acc[r][cc] = __builtin_fmaf(hr[r], wc[cc], acc[r][cc]);
  }

#pragma unroll
  for (int r = 0; r < 4; ++r) {
    size_t rowm = row0 + 4 * rg + r;
    PreT* dst = pre + rowm * 256 + c0 + 8 * cg;
#pragma unroll
    for (int cc = 0; cc < 8; ++cc) dst[cc] = (PreT)acc[r][cc];
  }
}

// pre_b0[t,b,q] = b_ih[q]+b_hh[q] + w[q,:]·h[b,t,:]
__global__ __launch_bounds__(256) void preb0_k(
    const float* __restrict__ h, const float* __restrict__ w,
    const float* __restrict__ bi, const float* __restrict__ bh,
    float* __restrict__ pre) {
  __shared__ float hs[64 * 68];
  const int tid = threadIdx.x;
  const int r = tid >> 2, q = tid & 3;

  float wr[64];
  {
    const float4* p = reinterpret_cast<const float4*>(w + q * 64);
#pragma unroll
    for (int i = 0; i < 16; ++i) {
      float4 v = p[i];
      wr[4 * i] = v.x; wr[4 * i + 1] = v.y; wr[4 * i + 2] = v.z; wr[4 * i + 3] = v.w;
    }
  }
  const float bias = bi[q] + bh[q];

  const size_t base = (size_t)blockIdx.x * 64;
  {
    const float4* src = reinterpret_cast<const float4*>(h + base * 64);
#pragma unroll
    for (int i = 0; i < 4; ++i) {
      int f = tid + 256 * i;
      int rr = f >> 4, kk = f & 15;
      *reinterpret_cast<float4*>(hs + rr * 68 + kk * 4) = src[f];
    }
  }
  __syncthreads();

  const float4* hr = reinterpret_cast<const float4*>(hs + r * 68);
  float a0 = bias, a1 = 0.f, a2 = 0.f, a3 = 0.f;
#pragma unroll
  for (int i = 0; i < 16; ++i) {
    float4 hv = hr[i];
    a0 = __builtin_fmaf(wr[4 * i], hv.x, a0);
    a1 = __builtin_fmaf(wr[4 * i + 1], hv.y, a1);
    a2 = __builtin_fmaf(wr[4 * i + 2], hv.z, a2);
    a3 = __builtin_fmaf(wr[4 * i + 3], hv.w, a3);
  }
  const size_t rowg = base + r;
  const int b = (int)(rowg / TT), t = (int)(rowg % TT);
  pre[((size_t)t * BB + b) * 4 + q] = (a0 + a1) + (a2 + a3);
}

// Fused b0->b1->b2, chunk-8 register pipeline (static indices).
__global__ __launch_bounds__(64, 1) void b_rec_k(
    const float* __restrict__ pre,  // [T,B,4]
    const float* __restrict__ w_hh_b0,
    const float* __restrict__ w_ih_b1, const float* __restrict__ w_hh_b1,
    const float* __restrict__ b_ih_b1, const float* __restrict__ b_hh_b1,
    const float* __restrict__ w_ih_b2, const float* __restrict__ w_hh_b2,
    const float* __restrict__ b_ih_b2, const float* __restrict__ b_hh_b2,
    float* __restrict__ out) {
  const int b = blockIdx.x * 64 + threadIdx.x;
  float wh0[4], wi1[4], wh1[4], bb1[4], wi2[4], wh2[4], bb2[4];
#pragma unroll
  for (int k = 0; k < 4; ++k) {
    wh0[k] = w_hh_b0[k];
    wi1[k] = w_ih_b1[k]; wh1[k] = w_hh_b1[k]; bb1[k] = b_ih_b1[k] + b_hh_b1[k];
    wi2[k] = w_ih_b2[k]; wh2[k] = w_hh_b2[k]; bb2[k] = b_ih_b2[k] + b_hh_b2[k];
  }
  float h0 = 0.f, c0 = 0.f, h1 = 0.f, c1 = 0.f, h2 = 0.f, c2 = 0.f;

  const float4* pp = reinterpret_cast<const float4*>(pre);
  float4 cur[8], nxt[8];
#pragma unroll
  for (int u = 0; u < 8; ++u) cur[u] = pp[u * BB + b];
#pragma unroll
  for (int u = 0; u < 8; ++u) nxt[u] = pp[(8 + u) * BB + b];

  for (int tb = 0; tb < TT; tb += 8) {
    float ob[8];
#pragma unroll
    for (int u = 0; u < 8; ++u) {
      float4 p = cur[u];
      float i0 = sig_(__builtin_fmaf(wh0[0], h0, p.x));
      float f0 = sig_(__builtin_fmaf(wh0[1], h0, p.y));
      float g0 = tanh_(__builtin_fmaf(wh0[2], h0, p.z));
      float o0 = sig_(__builtin_fmaf(wh0[3], h0, p.w));
      c0 = __builtin_fmaf(f0, c0, i0 * g0);
      h0 = o0 * tanh_(c0);

      float i1 = sig_(bb1[0] + __builtin_fmaf(wi1[0], h0, wh1[0] * h1));
      float f1 = sig_(bb1[1] + __builtin_fmaf(wi1[1], h0, wh1[1] * h1));
      float g1 = tanh_(bb1[2] + __builtin_fmaf(wi1[2], h0, wh1[2] * h1));
      float o1 = sig_(bb1[3] + __builtin_fmaf(wi1[3], h0, wh1[3] * h1));
      c1 = __builtin_fmaf(f1, c1, i1 * g1);
      h1 = o1 * tanh_(c1);

      float i2 = sig_(bb2[0] + __builtin_fmaf(wi2[0], h1, wh2[0] * h2));
      float f2 = sig_(bb2[1] + __builtin_fmaf(wi2[1], h1, wh2[1] * h2));
      float g2 = tanh_(bb2[2] + __builtin_fmaf(wi2[2], h1, wh2[2] * h2));
      float o2 = sig_(bb2[3] + __builtin_fmaf(wi2[3], h1, wh2[3] * h2));
      c2 = __builtin_fmaf(f2, c2, i2 * g2);
      h2 = o2 * tanh_(c2);
      ob[u] = h2;
    }
    float4 s0 = {ob[0], ob[1], ob[2], ob[3]};
    float4 s1 = {ob[4], ob[5], ob[6], ob[7]};
    float4* op = reinterpret_cast<float4*>(out + (size_t)b * TT + tb);
    op[0] = s0;
    op[1] = s1;
#pragma unroll
    for (int u = 0; u < 8; ++u) cur[u] = nxt[u];
    if (tb + 16 < TT) {
#pragma unroll
      for (int u = 0; u < 8; ++u) nxt[u] = pp[(tb + 16 + u) * BB + b];
    }
  }
}

template <typename PreT>
static void launch_all(void* const* d_in, void* d_out, void* d_ws, hipStream_t stream) {
  const float* x      = (const float*)d_in[0];
  const float* wih_a0 = (const float*)d_in[1];
  const float* whh_a0 = (const float*)d_in[2];
  const float* bih_a0 = (const float*)d_in[3];
  const float* bhh_a0 = (const float*)d_in[4];
  const float* wih_a1 = (const float*)d_in[5];
  const float* whh_a1 = (const float*)d_in[6];
  const float* bih_a1 = (const float*)d_in[7];
  const float* bhh_a1 = (const float*)d_in[8];
  const float* wih_a2 = (const float*)d_in[9];
  const float* whh_a2 = (const float*)d_in[10];
  const float* bih_a2 = (const float*)d_in[11];
  const float* bhh_a2 = (const float*)d_in[12];
  const float* wih_b0 = (const float*)d_in[13];
  const float* whh_b0 = (const float*)d_in[14];
  const float* bih_b0 = (const float*)d_in[15];
  const float* bhh_b0 = (const float*)d_in[16];
  const float* wih_b1 = (const float*)d_in[17];
  const float* whh_b1 = (const float*)d_in[18];
  const float* bih_b1 = (const float*)d_in[19];
  const float* bhh_b1 = (const float*)d_in[20];
  const float* wih_b2 = (const float*)d_in[21];
  const float* whh_b2 = (const float*)d_in[22];
  const float* bih_b2 = (const float*)d_in[23];
  const float* bhh_b2 = (const float*)d_in[24];

  const size_t M = (size_t)BB * TT;
  PreT* P   = (PreT*)d_ws;                                     // [M,256]
  float* hA = (float*)((char*)d_ws + M * 256 * sizeof(PreT));  // [M,64]
  float* pb0 = hA + M * 64;                                    // [T,B,4]
  float* out = (float*)d_out;

  rec_k<0, PreT><<<BB, 256, 0, stream>>>(x, nullptr, wih_a0, whh_a0, bih_a0, bhh_a0, hA);
  proj_k<PreT><<<(int)(M / 64) * 2, 256, 0, stream>>>(hA, wih_a1, P);
  rec_k<1, PreT><<<BB, 256, 0, stream>>>(nullptr, P, nullptr, whh_a1, bih_a1, bhh_a1, hA);
  proj_k<PreT><<<(int)(M / 64) * 2, 256, 0, stream>>>(hA, wih_a2, P);
  rec_k<1, PreT><<<BB, 256, 0, stream>>>(nullptr, P, nullptr, whh_a2, bih_a2, bhh_a2, hA);
  preb0_k<<<(int)(M / 64), 256, 0, stream>>>(hA, wih_b0, bih_b0, bhh_b0, pb0);
  b_rec_k<<<4, 64, 0, stream>>>(pb0, whh_b0, wih_b1, whh_b1, bih_b1, bhh_b1,
                                wih_b2, whh_b2, bih_b2, bhh_b2, out);
}

extern "C" void kernel_launch(void* const* d_in, const int* in_sizes, int n_in,
                              void* d_out, int out_size, void* d_ws, size_t ws_size,
                              hipStream_t stream) {
  const size_t M = (size_t)BB * TT;
  const size_t need_f32 = M * 256 * 4 + M * 64 * 4 + (size_t)TT * BB * 4 * 4;
  if (ws_size >= need_f32) launch_all<float>(d_in, d_out, d_ws, stream);
  else launch_all<_Float16>(d_in, d_out, d_ws, stream);
}